// Round 2
// baseline (1335.641 us; speedup 1.0000x reference)
//
#include <hip/hip_runtime.h>
#include <cmath>

#define BB 16
#define TT 600
#define VV 20000
#define EE 300
#define HH 512

typedef unsigned short ushort_t;
using bf16x8 = __attribute__((ext_vector_type(8))) __bf16;
using f32x4  = __attribute__((ext_vector_type(4))) float;

// ---------------- workspace layout ----------------
// fp32 region (offsets in floats)
#define OFF_KEYS_G 0
#define OFF_KEYS_C 4915200
#define OFF_SG     9830400
#define OFF_SC     9840000
#define OFF_CTX    9849600
#define OFF_QG     9857792
#define OFF_QC     9865984
#define OFF_RMAX   9874176
#define OFF_RSUM   9874192
#define OFF_SW     9874208
#define OFF_BF     9874432   // bf16 region starts here (float offset)
// bf16 region (offsets in ushorts, relative to OFF_BF)
#define UOFF_ENCB   0
#define UOFF_WTAW2  4915200
#define UOFF_WTAW1  5439488
#define UOFF_WTH    5963776
#define UOFF_WT1    6488064   // 2048 x 1344
#define UOFF_WT2    9240576   // 2048 x 1024
#define UOFF_X1B    11337728  // 16 x 1344
#define UOFF_X2B    11359232  // 16 x 1024
#define UOFF_H2NB   11375616  // 16 x 512
#define UOFF_X3B    11383808  // 16 x 1024

// copy-prob partials: 8 chunks x 16 b x 20000 v = 2.56M floats, reuses keys_g
// (keys_g is dead after k_scores; copyprob runs after k_softmax_t)
#define NCH 8
#define TCH 75
// logits partials: 4 kchunks x 16 b x 20000 v = 1.28M floats, reuses keys_c

__device__ __forceinline__ float sigmoidf_(float x) { return 1.0f / (1.0f + expf(-x)); }

__device__ __forceinline__ ushort_t f2bf(float f) {
    unsigned int u = __float_as_uint(f);
    u = (u + 0x7FFFu + ((u >> 16) & 1u)) >> 16;
    return (ushort_t)u;
}

__device__ __forceinline__ bf16x8 ldb(const ushort_t* p) {
    return *(const bf16x8*)(const void*)p;
}

// ---------------- cast enc_outs fp32 -> bf16 ----------------
__global__ __launch_bounds__(256) void k_cast_enc(const float* __restrict__ src,
                                                  ushort_t* __restrict__ dst, int n4) {
    int gid = blockIdx.x * 256 + threadIdx.x;
    if (gid >= n4) return;
    float4 v = ((const float4*)src)[gid];
    unsigned long long p = (unsigned long long)f2bf(v.x)
                         | ((unsigned long long)f2bf(v.y) << 16)
                         | ((unsigned long long)f2bf(v.z) << 32)
                         | ((unsigned long long)f2bf(v.w) << 48);
    *(unsigned long long*)(dst + (size_t)gid * 4) = p;
}

// ---------------- merged transpose+cast of all 7 weight jobs ----------------
// out[n][k] = bf16(W[k][n]), W = [A;B] stacked, pad K to Kp
__global__ __launch_bounds__(256) void k_tcast_all(
        const float* __restrict__ aw2g, const float* __restrict__ aw2c,
        const float* __restrict__ aw1g, const float* __restrict__ aw1c,
        const float* __restrict__ Wh,
        const float* __restrict__ k1, const float* __restrict__ r1,
        const float* __restrict__ k2, const float* __restrict__ r2,
        ushort_t* __restrict__ WtA2, ushort_t* __restrict__ WtA1,
        ushort_t* __restrict__ WtH, ushort_t* __restrict__ Wt1,
        ushort_t* __restrict__ Wt2) {
    __shared__ float tile[32][33];
    int bid = blockIdx.x;
    const float* A; const float* Bsrc; int Ka, Kb, N, Kp, local; ushort_t* out;
    if (bid < 1024) {            // 4x 512x512 attention mats, 256 tiles each
        int j = bid >> 8; local = bid & 255;
        A = (j == 0) ? aw2g : (j == 1) ? aw2c : (j == 2) ? aw1g : aw1c;
        Bsrc = nullptr; Ka = 512; Kb = 0; N = 512; Kp = 512;
        out = ((j < 2) ? WtA2 : WtA1) + (size_t)(j & 1) * 262144;
    } else if (bid < 1536) {     // Wh: 1024x512, 512 tiles
        local = bid - 1024; A = Wh; Bsrc = nullptr; Ka = 1024; Kb = 0; N = 512; Kp = 1024; out = WtH;
    } else if (bid < 4224) {     // k1;r1 -> 1344(pad) x 2048, 64x42 tiles
        local = bid - 1536; A = k1; Bsrc = r1; Ka = 812; Kb = 512; N = 2048; Kp = 1344; out = Wt1;
    } else {                     // k2;r2 -> 1024 x 2048, 64x32 tiles
        local = bid - 4224; A = k2; Bsrc = r2; Ka = 512; Kb = 512; N = 2048; Kp = 1024; out = Wt2;
    }
    int ntx = N >> 5;
    int tx = local & (ntx - 1), ty = local / ntx;
    int nb = tx * 32, kb = ty * 32;
    int tid = threadIdx.x;
    int K = Ka + Kb;
    for (int kk = tid >> 5; kk < 32; kk += 8) {
        int k = kb + kk, n = nb + (tid & 31);
        float v = 0.f;
        if (k < Ka)      v = A[(size_t)k * N + n];
        else if (k < K)  v = Bsrc[(size_t)(k - Ka) * N + n];
        tile[kk][tid & 31] = v;
    }
    __syncthreads();
    for (int nn = tid >> 5; nn < 32; nn += 8) {
        int n = nb + nn, k = kb + (tid & 31);
        out[(size_t)n * Kp + k] = f2bf(tile[tid & 31][nn]);
    }
}

// ---------------- prep: X1b = bf16[emb|lha|h1|pad], X2b right half = bf16(h2), zero ctx ----------------
__global__ __launch_bounds__(256) void k_prep(const int* __restrict__ x, const float* __restrict__ emb,
        const float* __restrict__ lha, const float* __restrict__ h1, const float* __restrict__ h2,
        ushort_t* __restrict__ X1b, ushort_t* __restrict__ X2b, float* __restrict__ ctx) {
    int gid = blockIdx.x * 256 + threadIdx.x;
    if (gid < BB * 1344) {
        int b = gid / 1344, i = gid - b * 1344;
        float v = 0.f;
        if (i < EE)             v = emb[(size_t)x[b] * EE + i];
        else if (i < EE + HH)   v = lha[b * HH + (i - EE)];
        else if (i < EE + 2*HH) v = h1[b * HH + (i - EE - HH)];
        X1b[gid] = f2bf(v);
    } else if (gid < BB * 1344 + BB * HH) {
        int r = gid - BB * 1344;
        int b = r >> 9, i = r & 511;
        X2b[b * 1024 + 512 + i] = f2bf(h2[b * HH + i]);
    } else if (gid < BB * 1344 + 2 * BB * HH) {
        ctx[gid - BB * 1344 - BB * HH] = 0.f;
    }
}

// ---------------- keys = enc_outs @ aw2{g,c} via MFMA: (9600x512)@(512x512) ----------------
__global__ __launch_bounds__(256) void k_keys_mfma(const ushort_t* __restrict__ encb,
        const ushort_t* __restrict__ Wt_aw2, float* __restrict__ keys_g, float* __restrict__ keys_c) {
    int wave = threadIdx.x >> 6, lane = threadIdx.x & 63;
    int quad = lane >> 4, l16 = lane & 15;
    int m0 = (blockIdx.x * 4 + wave) * 16;
    int n0 = blockIdx.y * 64;
    const ushort_t* Wt = Wt_aw2 + (size_t)blockIdx.z * HH * HH;
    float* keys = blockIdx.z ? keys_c : keys_g;
    const ushort_t* arow = encb + (size_t)(m0 + l16) * HH + quad * 8;
    const ushort_t* brow = Wt + (size_t)(n0 + l16) * HH + quad * 8;
    f32x4 a0 = {0.f,0.f,0.f,0.f}, a1 = a0, a2 = a0, a3 = a0;
    for (int kk = 0; kk < HH; kk += 32) {
        bf16x8 a = ldb(arow + kk);
        a0 = __builtin_amdgcn_mfma_f32_16x16x32_bf16(a, ldb(brow + kk), a0, 0, 0, 0);
        a1 = __builtin_amdgcn_mfma_f32_16x16x32_bf16(a, ldb(brow + (size_t)16 * HH + kk), a1, 0, 0, 0);
        a2 = __builtin_amdgcn_mfma_f32_16x16x32_bf16(a, ldb(brow + (size_t)32 * HH + kk), a2, 0, 0, 0);
        a3 = __builtin_amdgcn_mfma_f32_16x16x32_bf16(a, ldb(brow + (size_t)48 * HH + kk), a3, 0, 0, 0);
    }
#pragma unroll
    for (int r = 0; r < 4; ++r) {
        int m = m0 + quad * 4 + r;
        keys[(size_t)m * HH + n0 + l16]      = a0[r];
        keys[(size_t)m * HH + n0 + 16 + l16] = a1[r];
        keys[(size_t)m * HH + n0 + 32 + l16] = a2[r];
        keys[(size_t)m * HH + n0 + 48 + l16] = a3[r];
    }
}

// ---------------- LSTM via MFMA, fused activation. z = Xb(16 x Kp) @ W(K x 2048) ----------------
__global__ __launch_bounds__(256) void k_lstm_mfma(const ushort_t* __restrict__ Xb,
        const ushort_t* __restrict__ Wt, int Kp, const float* __restrict__ bias,
        const float* __restrict__ c_old, float* __restrict__ h_new, float* __restrict__ c_new,
        ushort_t* __restrict__ hb, int hb_stride) {
    int wave = threadIdx.x >> 6, lane = threadIdx.x & 63;
    int quad = lane >> 4, l16 = lane & 15;
    int j0 = (blockIdx.x * 4 + wave) * 16;              // 0..496
    const ushort_t* arow = Xb + (size_t)l16 * Kp + quad * 8;
    const ushort_t* brow = Wt + (size_t)(j0 + l16) * Kp + quad * 8;
    f32x4 zi = {0.f,0.f,0.f,0.f}, zf = zi, zg = zi, zo = zi;
    for (int kk = 0; kk < Kp; kk += 32) {
        bf16x8 a = ldb(arow + kk);
        zi = __builtin_amdgcn_mfma_f32_16x16x32_bf16(a, ldb(brow + kk), zi, 0, 0, 0);
        zf = __builtin_amdgcn_mfma_f32_16x16x32_bf16(a, ldb(brow + (size_t)512 * Kp + kk), zf, 0, 0, 0);
        zg = __builtin_amdgcn_mfma_f32_16x16x32_bf16(a, ldb(brow + (size_t)1024 * Kp + kk), zg, 0, 0, 0);
        zo = __builtin_amdgcn_mfma_f32_16x16x32_bf16(a, ldb(brow + (size_t)1536 * Kp + kk), zo, 0, 0, 0);
    }
    int n = j0 + l16;
#pragma unroll
    for (int r = 0; r < 4; ++r) {
        int bi = quad * 4 + r;
        float I = sigmoidf_(zi[r] + bias[n]);
        float F = sigmoidf_(zf[r] + bias[512 + n]);
        float G = tanhf(zg[r] + bias[1024 + n]);
        float O = sigmoidf_(zo[r] + bias[1536 + n]);
        float c = F * c_old[bi * HH + n] + I * G;
        float h = O * tanhf(c);
        c_new[bi * HH + n] = c;
        h_new[bi * HH + n] = h;
        hb[(size_t)bi * hb_stride + n] = f2bf(h);
    }
}

// ---------------- q = h2n @ aw1{g,c} via MFMA ----------------
__global__ __launch_bounds__(256) void k_qproj_mfma(const ushort_t* __restrict__ h2nb,
        const ushort_t* __restrict__ Wt_aw1, float* __restrict__ qg, float* __restrict__ qc) {
    int wave = threadIdx.x >> 6, lane = threadIdx.x & 63;
    int quad = lane >> 4, l16 = lane & 15;
    int j0 = (blockIdx.x * 4 + wave) * 16;
    const ushort_t* Wt = Wt_aw1 + (size_t)blockIdx.y * HH * HH;
    float* q = blockIdx.y ? qc : qg;
    const ushort_t* arow = h2nb + (size_t)l16 * HH + quad * 8;
    const ushort_t* brow = Wt + (size_t)(j0 + l16) * HH + quad * 8;
    f32x4 acc = {0.f,0.f,0.f,0.f};
    for (int kk = 0; kk < HH; kk += 32)
        acc = __builtin_amdgcn_mfma_f32_16x16x32_bf16(ldb(arow + kk), ldb(brow + kk), acc, 0, 0, 0);
#pragma unroll
    for (int r = 0; r < 4; ++r)
        q[(quad * 4 + r) * HH + j0 + l16] = acc[r];
}

// ---------------- hidden = tanh(X3 @ Wh + bh) via MFMA, K=1024 ----------------
__global__ __launch_bounds__(256) void k_hidden_mfma(const ushort_t* __restrict__ X3b,
        const ushort_t* __restrict__ WtH, const float* __restrict__ bh, float* __restrict__ hid) {
    int wave = threadIdx.x >> 6, lane = threadIdx.x & 63;
    int quad = lane >> 4, l16 = lane & 15;
    int j0 = (blockIdx.x * 4 + wave) * 16;
    const ushort_t* arow = X3b + (size_t)l16 * 1024 + quad * 8;
    const ushort_t* brow = WtH + (size_t)(j0 + l16) * 1024 + quad * 8;
    f32x4 acc = {0.f,0.f,0.f,0.f};
    for (int kk = 0; kk < 1024; kk += 32)
        acc = __builtin_amdgcn_mfma_f32_16x16x32_bf16(ldb(arow + kk), ldb(brow + kk), acc, 0, 0, 0);
    int n = j0 + l16;
#pragma unroll
    for (int r = 0; r < 4; ++r)
        hid[(quad * 4 + r) * HH + n] = tanhf(acc[r] + bh[n]);
}

// ---------------- score[b,t] = sum_h tanh(q+key)*v ----------------
__global__ __launch_bounds__(256) void k_scores(const float* __restrict__ keys_g,
        const float* __restrict__ keys_c, const float* __restrict__ qg, const float* __restrict__ qc,
        const float* __restrict__ avg, const float* __restrict__ avc,
        float* __restrict__ sg, float* __restrict__ sc) {
    int gw = blockIdx.x * 4 + (threadIdx.x >> 6);
    int lane = threadIdx.x & 63;
    int variant = (gw >= BB * TT) ? 1 : 0;
    int r = variant ? (gw - BB * TT) : gw;
    int b = r / TT;
    const float* q = (variant ? qc : qg) + b * HH;
    const float* key = (variant ? keys_c : keys_g) + (size_t)r * HH;
    const float* v = variant ? avc : avg;
    float s = 0.f;
    for (int h = lane; h < HH; h += 64) s += tanhf(q[h] + key[h]) * v[h];
    for (int off = 32; off; off >>= 1) s += __shfl_down(s, off);
    if (lane == 0) (variant ? sc : sg)[r] = s;
}

// ---------------- softmax over T, in place ----------------
__global__ void k_softmax_t(float* __restrict__ sg, float* __restrict__ sc) {
    __shared__ float sv[TT];
    __shared__ float red[256];
    int b = blockIdx.x & 15, variant = blockIdx.x >> 4;
    float* s = (variant ? sc : sg) + b * TT;
    int tid = threadIdx.x;
    float m = -1e30f;
    for (int i = tid; i < TT; i += 256) { sv[i] = s[i]; m = fmaxf(m, sv[i]); }
    red[tid] = m; __syncthreads();
    for (int off = 128; off; off >>= 1) { if (tid < off) red[tid] = fmaxf(red[tid], red[tid + off]); __syncthreads(); }
    m = red[0]; __syncthreads();
    float sum = 0.f;
    for (int i = tid; i < TT; i += 256) { float e = expf(sv[i] - m); sv[i] = e; sum += e; }
    red[tid] = sum; __syncthreads();
    for (int off = 128; off; off >>= 1) { if (tid < off) red[tid] += red[tid + off]; __syncthreads(); }
    float inv = 1.0f / red[0];
    __syncthreads();
    for (int i = tid; i < TT; i += 256) s[i] = sv[i] * inv;
}

// ---------------- copy_prob partials: part[tc][b][v] = sum_{t in chunk} align_c[b,t]*enc_ins[b,t,v] ----------------
// T split into NCH=8 chunks of TCH=75 -> 2560 blocks (40 waves/CU) to hide HBM latency on the 768MB stream
__global__ __launch_bounds__(256) void k_copyprob(const float* __restrict__ align_c,
        const float* __restrict__ enc_ins, float* __restrict__ part) {
    __shared__ float sa[TCH];
    int b = blockIdx.z, tc = blockIdx.y, tid = threadIdx.x;
    if (tid < TCH) sa[tid] = align_c[b * TT + tc * TCH + tid];
    __syncthreads();
    int v4 = blockIdx.x * 256 + tid;
    if (v4 >= VV / 4) return;
    const float4* e = (const float4*)enc_ins + (size_t)b * TT * (VV / 4)
                    + (size_t)tc * TCH * (VV / 4) + v4;
    float4 p0 = {0,0,0,0}, p1 = p0, p2 = p0, p3 = p0, p4 = p0;
    for (int t = 0; t < TCH; t += 5) {
        float4 e0 = e[(size_t)(t + 0) * (VV / 4)];
        float4 e1 = e[(size_t)(t + 1) * (VV / 4)];
        float4 e2 = e[(size_t)(t + 2) * (VV / 4)];
        float4 e3 = e[(size_t)(t + 3) * (VV / 4)];
        float4 e4 = e[(size_t)(t + 4) * (VV / 4)];
        float c0 = sa[t], c1 = sa[t+1], c2 = sa[t+2], c3 = sa[t+3], c4 = sa[t+4];
        p0.x += c0*e0.x; p0.y += c0*e0.y; p0.z += c0*e0.z; p0.w += c0*e0.w;
        p1.x += c1*e1.x; p1.y += c1*e1.y; p1.z += c1*e1.z; p1.w += c1*e1.w;
        p2.x += c2*e2.x; p2.y += c2*e2.y; p2.z += c2*e2.z; p2.w += c2*e2.w;
        p3.x += c3*e3.x; p3.y += c3*e3.y; p3.z += c3*e3.z; p3.w += c3*e3.w;
        p4.x += c4*e4.x; p4.y += c4*e4.y; p4.z += c4*e4.z; p4.w += c4*e4.w;
    }
    float4 s;
    s.x = p0.x + p1.x + p2.x + p3.x + p4.x;
    s.y = p0.y + p1.y + p2.y + p3.y + p4.y;
    s.z = p0.z + p1.z + p2.z + p3.z + p4.z;
    s.w = p0.w + p1.w + p2.w + p3.w + p4.w;
    ((float4*)part)[(size_t)(tc * BB + b) * (VV / 4) + v4] = s;
}

// ---------------- context[b,h] = sum_t align_g[b,t]*enc_outs[b,t,h] ----------------
__global__ void k_context(const float* __restrict__ align_g, const float* __restrict__ enc_outs,
                          float* __restrict__ ctx) {
    __shared__ float sa[150];
    int b = blockIdx.y, tc = blockIdx.x;
    int tid = threadIdx.x;  // 512
    if (tid < 150) sa[tid] = align_g[b * TT + tc * 150 + tid];
    __syncthreads();
    const float* e = enc_outs + (size_t)(b * TT + tc * 150) * HH + tid;
    float acc = 0.f;
#pragma unroll 6
    for (int t = 0; t < 150; ++t) acc += sa[t] * e[(size_t)t * HH];
    atomicAdd(&ctx[b * HH + tid], acc);
}

// ---------------- X3b = bf16[ctx | h2n] ----------------
__global__ __launch_bounds__(256) void k_ctxcast(const float* __restrict__ ctx,
        const float* __restrict__ h2n, ushort_t* __restrict__ X3b) {
    int gid = blockIdx.x * 256 + threadIdx.x;   // 16*1024
    int b = gid >> 10, i = gid & 1023;
    float v = (i < HH) ? ctx[b * HH + i] : h2n[b * HH + (i - HH)];
    X3b[gid] = f2bf(v);
}

// ---------------- switch = sigmoid(hid @ Wf + bf) ----------------
__global__ void k_switch(const float* __restrict__ hid, const float* __restrict__ Wf,
                         const float* __restrict__ bf, float* __restrict__ sw) {
    int b = threadIdx.x >> 6, lane = threadIdx.x & 63;
    float s = 0.f;
    for (int j = lane; j < HH; j += 64) s += hid[b * HH + j] * Wf[j];
    for (int off = 32; off; off >>= 1) s += __shfl_down(s, off);
    if (lane == 0) sw[b] = sigmoidf_(s + bf[0]);
}

// ---------------- logits partial: part_l[(c*BB+b)*VV + v] = sum_{k in chunk} hid[b][k]*Wg[k][v] ----------------
// K=512 split into 4 chunks of 128 -> (79,4) blocks; no atomics, partials into dead keys_c
__global__ __launch_bounds__(256) void k_logits_part(const float* __restrict__ hid,
        const float* __restrict__ Wg, float* __restrict__ part_l) {
    __shared__ float sh[BB * 128];
    int tid = threadIdx.x;
    int k0 = blockIdx.y * 128;
    for (int i = tid; i < BB * 128; i += 256) {
        int b = i >> 7, kk = i & 127;
        sh[i] = hid[b * HH + k0 + kk];
    }
    __syncthreads();
    int v = blockIdx.x * 256 + tid;
    if (v >= VV) return;
    float acc[BB] = {};
#pragma unroll 8
    for (int kk = 0; kk < 128; ++kk) {
        float w = Wg[(size_t)(k0 + kk) * VV + v];
#pragma unroll
        for (int b = 0; b < BB; ++b) acc[b] += sh[b * 128 + kk] * w;
    }
#pragma unroll
    for (int b = 0; b < BB; ++b)
        part_l[(size_t)(blockIdx.y * BB + b) * VV + v] = acc[b];
}

// ---------------- logits reduce: sum 4 partials + bg -> out; compute rmax/rsum ----------------
__global__ void k_logits_red(const float* __restrict__ part_l, const float* __restrict__ bg,
                             float* __restrict__ out, float* __restrict__ rmax,
                             float* __restrict__ rsum) {
    __shared__ float red[1024];
    int b = blockIdx.x, tid = threadIdx.x;
    float* l = out + (size_t)b * VV;
    float m = -1e30f;
    for (int v = tid; v < VV; v += 1024) {
        float s = bg[v]
                + part_l[(size_t)(0 * BB + b) * VV + v]
                + part_l[(size_t)(1 * BB + b) * VV + v]
                + part_l[(size_t)(2 * BB + b) * VV + v]
                + part_l[(size_t)(3 * BB + b) * VV + v];
        l[v] = s;
        m = fmaxf(m, s);
    }
    red[tid] = m; __syncthreads();
    for (int off = 512; off; off >>= 1) { if (tid < off) red[tid] = fmaxf(red[tid], red[tid + off]); __syncthreads(); }
    m = red[0]; __syncthreads();
    float s = 0.f;
    for (int v = tid; v < VV; v += 1024) s += expf(l[v] - m);
    red[tid] = s; __syncthreads();
    for (int off = 512; off; off >>= 1) { if (tid < off) red[tid] += red[tid + off]; __syncthreads(); }
    if (tid == 0) { rmax[b] = m; rsum[b] = red[0]; }
}

// ---------------- final: out = softmax(logits)*(1-sw) + (sum_c part[c])*sw ----------------
__global__ __launch_bounds__(256) void k_final(const float* __restrict__ part,
        const float* __restrict__ rmax, const float* __restrict__ rsum,
        const float* __restrict__ sw, float* __restrict__ out) {
    int b = blockIdx.y;
    int v4 = blockIdx.x * 256 + threadIdx.x;
    if (v4 >= VV / 4) return;
    const float4* pp = (const float4*)part + v4;
    float4 cp = {0, 0, 0, 0};
#pragma unroll
    for (int c = 0; c < NCH; ++c) {
        float4 t = pp[(size_t)(c * BB + b) * (VV / 4)];
        cp.x += t.x; cp.y += t.y; cp.z += t.z; cp.w += t.w;
    }
    float m = rmax[b], inv = 1.0f / rsum[b], s = sw[b], os = 1.0f - s;
    float4* op = (float4*)(out + (size_t)b * VV) + v4;
    float4 l4 = *op;
    float4 r;
    r.x = expf(l4.x - m) * inv * os + cp.x * s;
    r.y = expf(l4.y - m) * inv * os + cp.y * s;
    r.z = expf(l4.z - m) * inv * os + cp.z * s;
    r.w = expf(l4.w - m) * inv * os + cp.w * s;
    *op = r;
}

extern "C" void kernel_launch(void* const* d_in, const int* in_sizes, int n_in,
                              void* d_out, int out_size, void* d_ws, size_t ws_size,
                              hipStream_t stream) {
    const int*   x        = (const int*)d_in[0];
    const float* lha      = (const float*)d_in[1];
    const float* h1       = (const float*)d_in[2];
    const float* c1       = (const float*)d_in[3];
    const float* h2       = (const float*)d_in[4];
    const float* c2       = (const float*)d_in[5];
    const float* enc_outs = (const float*)d_in[6];
    const float* enc_ins  = (const float*)d_in[7];
    const float* emb      = (const float*)d_in[8];
    const float* k1       = (const float*)d_in[9];
    const float* r1       = (const float*)d_in[10];
    const float* b1       = (const float*)d_in[11];
    const float* k2       = (const float*)d_in[12];
    const float* r2       = (const float*)d_in[13];
    const float* b2       = (const float*)d_in[14];
    const float* Wh       = (const float*)d_in[15];
    const float* bh       = (const float*)d_in[16];
    const float* Wg       = (const float*)d_in[17];
    const float* bg       = (const float*)d_in[18];
    const float* Wf       = (const float*)d_in[19];
    const float* bf       = (const float*)d_in[20];
    const float* aw1g     = (const float*)d_in[21];
    const float* aw2g     = (const float*)d_in[22];
    const float* avg      = (const float*)d_in[23];
    const float* aw1c     = (const float*)d_in[24];
    const float* aw2c     = (const float*)d_in[25];
    const float* avc      = (const float*)d_in[26];

    float* ws = (float*)d_ws;
    float* keys_g = ws + OFF_KEYS_G;
    float* keys_c = ws + OFF_KEYS_C;
    float* sg     = ws + OFF_SG;
    float* sc     = ws + OFF_SC;
    float* ctx    = ws + OFF_CTX;
    float* qg     = ws + OFF_QG;
    float* qc     = ws + OFF_QC;
    float* rmax   = ws + OFF_RMAX;
    float* rsum   = ws + OFF_RSUM;
    float* swbuf  = ws + OFF_SW;
    float* cp_part = keys_g;   // reuse: keys dead after k_scores; copyprob runs after k_softmax_t
    float* lg_part = keys_c;   // reuse: logits partials (4*16*20000 floats)
    ushort_t* wsb   = (ushort_t*)(ws + OFF_BF);
    ushort_t* encb  = wsb + UOFF_ENCB;
    ushort_t* WtA2  = wsb + UOFF_WTAW2;
    ushort_t* WtA1  = wsb + UOFF_WTAW1;
    ushort_t* WtH   = wsb + UOFF_WTH;
    ushort_t* Wt1   = wsb + UOFF_WT1;
    ushort_t* Wt2   = wsb + UOFF_WT2;
    ushort_t* X1b   = wsb + UOFF_X1B;
    ushort_t* X2b   = wsb + UOFF_X2B;
    ushort_t* h2nb  = wsb + UOFF_H2NB;
    ushort_t* X3b   = wsb + UOFF_X3B;

    float* out     = (float*)d_out;
    float* out_res = out;
    float* out_hid = out + 320000;
    float* out_h1n = out + 328192;
    float* out_c1n = out + 336384;
    float* out_h2n = out + 344576;
    float* out_c2n = out + 352768;

    // casts (independent) — merged into 3 launches
    k_cast_enc<<<4800, 256, 0, stream>>>(enc_outs, encb, BB * TT * HH / 4);
    k_tcast_all<<<6272, 256, 0, stream>>>(aw2g, aw2c, aw1g, aw1c, Wh, k1, r1, k2, r2,
                                          WtA2, WtA1, WtH, Wt1, Wt2);
    k_prep<<<148, 256, 0, stream>>>(x, emb, lha, h1, h2, X1b, X2b, ctx);

    // keys GEMM (MFMA)
    k_keys_mfma<<<dim3(150, 8, 2), 256, 0, stream>>>(encb, WtA2, keys_g, keys_c);

    // LSTM chain (MFMA, fused activation)
    k_lstm_mfma<<<8, 256, 0, stream>>>(X1b, Wt1, 1344, b1, c1, out_h1n, out_c1n, X2b, 1024);
    k_lstm_mfma<<<8, 256, 0, stream>>>(X2b, Wt2, 1024, b2, c2, out_h2n, out_c2n, h2nb, 512);

    // attention
    k_qproj_mfma<<<dim3(8, 2), 256, 0, stream>>>(h2nb, WtA1, qg, qc);
    k_scores<<<(2 * BB * TT) / 4, 256, 0, stream>>>(keys_g, keys_c, qg, qc, avg, avc, sg, sc);
    k_softmax_t<<<32, 256, 0, stream>>>(sg, sc);

    // big copy-prob stream (768 MB) — high-occupancy T-chunked partials into dead keys_g
    k_copyprob<<<dim3(20, NCH, BB), 256, 0, stream>>>(sc, enc_ins, cp_part);

    k_context<<<dim3(4, BB), 512, 0, stream>>>(sg, enc_outs, ctx);
    k_ctxcast<<<64, 256, 0, stream>>>(ctx, out_h2n, X3b);

    // output head
    k_hidden_mfma<<<8, 256, 0, stream>>>(X3b, WtH, bh, out_hid);
    k_switch<<<1, 1024, 0, stream>>>(out_hid, Wf, bf, swbuf);
    k_logits_part<<<dim3((VV + 255) / 256, 4), 256, 0, stream>>>(out_hid, Wg, lg_part);
    k_logits_red<<<BB, 1024, 0, stream>>>(lg_part, bg, out_res, rmax, rsum);
    k_final<<<dim3(20, BB), 256, 0, stream>>>(cp_part, rmax, rsum, swbuf, out_res);
}